// Round 1
// baseline (250.270 us; speedup 1.0000x reference)
//
#include <hip/hip_runtime.h>

typedef __attribute__((ext_vector_type(8))) short bf16x8;
typedef __attribute__((ext_vector_type(4))) float f32x4;

#define MFMA16(a,b,c) __builtin_amdgcn_mfma_f32_16x16x32_bf16((a),(b),(c),0,0,0)

__device__ __forceinline__ unsigned short f2bf(float f){
  unsigned int u = __float_as_uint(f);
  unsigned int r = (u + 0x7fffu + ((u>>16)&1u)) >> 16;
  return (unsigned short)r;
}
__device__ __forceinline__ float bf2f(unsigned short h){
  return __uint_as_float(((unsigned int)h)<<16);
}
__device__ __forceinline__ float tanh_fast(float x){
  float e = __expf(2.f*x);
  return 1.f - 2.f/(e + 1.f);
}

// ---- workspace byte offsets ----
#define WS_W1H   0u           // [4 mt][8 kt][64 lane][8] bf16 hi  (32768 B)
#define WS_W1L   32768u
#define WS_WHHH  65536u       // [3][16 nt][8 kt][64][8] bf16 hi   (393216 B)
#define WS_WHHL  458752u
#define WS_Y1    851968u      // [640][64][10][10] f32             (16384000 B)
#define WS_Y2    17235968u    // [640][3] f32
#define WS_SEQ   17243648u    // [3][64][16] f32
#define WS_LAST  17255936u    // [3][16][256] f32

// ================= prep: split W1 / Whh into MFMA fragment layout =================
__global__ __launch_bounds__(256) void k_prep(const float* __restrict__ W1,
                                              const float* __restrict__ Whh,
                                              unsigned short* __restrict__ w1h,
                                              unsigned short* __restrict__ w1l,
                                              unsigned short* __restrict__ whh_h,
                                              unsigned short* __restrict__ whh_l){
  int t = blockIdx.x*256 + threadIdx.x;
  if (t < 2048){
    int l = t & 63, kt = (t>>6)&7, mt = t>>9;
    int co = mt*16 + (l&15);
    int k0 = kt*32 + ((l>>4)<<3);
    bf16x8 hv, lv;
    #pragma unroll
    for (int j=0;j<8;j++){
      int k = k0 + j;
      float v = (k < 243) ? W1[co*243 + k] : 0.f;
      unsigned short h = f2bf(v);
      unsigned short lo = f2bf(v - bf2f(h));
      hv[j] = (short)h; lv[j] = (short)lo;
    }
    *(bf16x8*)(w1h + (size_t)t*8) = hv;
    *(bf16x8*)(w1l + (size_t)t*8) = lv;
  } else if (t < 2048 + 24576){
    int u = t - 2048;
    int l = u & 63, kt = (u>>6)&7, nt = (u>>9)&15, rnn = u>>13;
    int o = nt*16 + (l&15);
    int k0 = kt*32 + ((l>>4)<<3);
    const float* src = Whh + ((size_t)rnn*256 + o)*256;
    bf16x8 hv, lv;
    #pragma unroll
    for (int j=0;j<8;j++){
      float v = src[k0 + j];
      unsigned short h = f2bf(v);
      unsigned short lo = f2bf(v - bf2f(h));
      hv[j] = (short)h; lv[j] = (short)lo;
    }
    *(bf16x8*)(whh_h + (size_t)u*8) = hv;
    *(bf16x8*)(whh_l + (size_t)u*8) = lv;
  }
}

// ================= conv1 (9x9 stride 9) + bias + relu + 2x2 maxpool =================
// block = (frame, group of 4 patch-rows); 256 threads = 4 waves = 4 co m-tiles
__global__ __launch_bounds__(256) void k_conv1(const float* __restrict__ x,
                                               const float* __restrict__ b1,
                                               const unsigned short* __restrict__ w1h,
                                               const unsigned short* __restrict__ w1l,
                                               float* __restrict__ y1){
  __shared__ __align__(16) char smem[81920];   // Bhi[80][256] bf16 | Blo at +40960; reused as pool[64][80] f32
  int fr = blockIdx.x / 5, g = blockIdx.x % 5;
  int t = threadIdx.x;
  // zero the K padding region k in [243,256)
  for (int i=t; i<1040; i+=256){
    int p = i/13, k = 243 + (i - p*13);
    int off = ((p<<9) + (k<<1)) ^ ((p&7)<<4);
    *(unsigned short*)(smem + off) = 0;
    *(unsigned short*)(smem + 40960 + off) = 0;
  }
  // stage 36 rows x 180 cols x 3c -> [patch][k] split-bf16, XOR-swizzled
  const float* xf = x + (size_t)fr*97200 + (size_t)g*6480;
  for (int c=0;c<3;c++){
    const float4* src = (const float4*)(xf + c*32400);
    for (int i=t; i<1620; i+=256){
      float4 v4 = src[i];
      float vv[4] = {v4.x, v4.y, v4.z, v4.w};
      int f0 = i*4;
      #pragma unroll
      for (int q=0;q<4;q++){
        int f = f0 + q;
        int row = f/180, col = f - row*180;
        int oyl = row/9,  ky = row - oyl*9;
        int ox  = col/9,  kx = col - ox*9;
        int p = oyl*20 + ox;
        int k = c*81 + ky*9 + kx;
        int off = ((p<<9) + (k<<1)) ^ ((p&7)<<4);
        float v = vv[q];
        unsigned short h = f2bf(v);
        unsigned short lo = f2bf(v - bf2f(h));
        *(unsigned short*)(smem + off) = h;
        *(unsigned short*)(smem + 40960 + off) = lo;
      }
    }
  }
  __syncthreads();
  int w = t>>6, l = t&63;
  // A = W1 fragments (preloaded, split)
  bf16x8 ah[8], al[8];
  #pragma unroll
  for (int kt=0; kt<8; kt++){
    size_t fi = (((size_t)(w*8 + kt))*64 + l)*8;
    ah[kt] = *(const bf16x8*)(w1h + fi);
    al[kt] = *(const bf16x8*)(w1l + fi);
  }
  f32x4 acc[5];
  #pragma unroll
  for (int nt=0;nt<5;nt++) acc[nt] = (f32x4){0.f,0.f,0.f,0.f};
  int colb = (l>>4)<<4;
  for (int nt=0; nt<5; nt++){
    int p = nt*16 + (l&15);
    int sw = (p&7)<<4;
    #pragma unroll
    for (int kt=0; kt<8; kt++){
      int off = ((p<<9) + (kt<<6) + colb) ^ sw;
      bf16x8 bh  = *(const bf16x8*)(smem + off);
      bf16x8 blo = *(const bf16x8*)(smem + 40960 + off);
      acc[nt] = MFMA16(ah[kt], bh,  acc[nt]);
      acc[nt] = MFMA16(ah[kt], blo, acc[nt]);
      acc[nt] = MFMA16(al[kt], bh,  acc[nt]);
    }
  }
  __syncthreads();           // done reading B tiles; reuse LDS as pool buffer
  float* poolb = (float*)smem;
  float bias[4];
  #pragma unroll
  for (int reg=0;reg<4;reg++) bias[reg] = b1[w*16 + ((l>>4)<<2) + reg];
  #pragma unroll
  for (int nt=0;nt<5;nt++){
    int p = nt*16 + (l&15);
    #pragma unroll
    for (int reg=0;reg<4;reg++){
      int co = w*16 + ((l>>4)<<2) + reg;    // C/D: col=lane&15 (patch), row=4*(lane>>4)+reg (co)
      float v = fmaxf(acc[nt][reg] + bias[reg], 0.f);
      poolb[co*80 + p] = v;
    }
  }
  __syncthreads();
  for (int idx=t; idx<1280; idx+=256){
    int co = idx/20, rem = idx - co*20;
    int pr = rem/10, px = rem - pr*10;
    int p0 = pr*40 + px*2;
    const float* pb = poolb + co*80 + p0;
    float m = fmaxf(fmaxf(pb[0], pb[1]), fmaxf(pb[20], pb[21]));
    y1[(((size_t)fr*64 + co)*10 + (size_t)(g*2+pr))*10 + px] = m;
  }
}

// ================= conv2 (5x5 stride 5) + bias + relu + 2x2 maxpool -> y[640][3] =================
__global__ __launch_bounds__(256) void k_conv2(const float* __restrict__ y1,
                                               const float* __restrict__ W2,
                                               const float* __restrict__ b2,
                                               float* __restrict__ y2){
  __shared__ float yl[6400];
  __shared__ float w2s[4800];
  int fr = blockIdx.x, t = threadIdx.x;
  const float4* src = (const float4*)(y1 + (size_t)fr*6400);
  for (int i=t;i<1600;i+=256) ((float4*)yl)[i] = src[i];
  for (int i=t;i<1200;i+=256) ((float4*)w2s)[i] = ((const float4*)W2)[i];
  __syncthreads();
  if (t < 192){
    int o = t>>4, l16 = t&15;
    int ch = o>>2, pos = o&3;
    int oy = pos>>1, ox = pos&1;
    float s = 0.f;
    for (int i=0;i<100;i++){
      int k = l16 + (i<<4);
      int ci = k/25; int r = k - ci*25; int ky = r/5, kx = r - ky*5;
      s += yl[ci*100 + (5*oy+ky)*10 + 5*ox + kx] * w2s[ch*1600 + k];
    }
    #pragma unroll
    for (int d=1; d<16; d<<=1) s += __shfl_xor(s, d);
    float v = fmaxf(s + b2[ch], 0.f);
    v = fmaxf(v, __shfl_xor(v, 16));
    v = fmaxf(v, __shfl_xor(v, 32));
    if ((t&63)==0) y2[fr*3 + (t>>6)] = v;
  }
}

// ================= BN (train) + per-sample range sort + build seqs[3][64][16] =================
__global__ __launch_bounds__(256) void k_bn(const float* __restrict__ y2,
                                            const float* __restrict__ gamma,
                                            const float* __restrict__ beta,
                                            float* __restrict__ seq){
  __shared__ float yl[1920];
  __shared__ float af[64], bfv[64];
  __shared__ float tsb[10][3][64];
  __shared__ float rngL[10][3];
  __shared__ int   perm[10][3];
  int t = threadIdx.x;
  for (int i=t;i<1920;i+=256) yl[i] = y2[i];
  __syncthreads();
  if (t < 64){
    float mu = 0.f;
    for (int b=0;b<10;b++)
      for (int ch=0;ch<3;ch++) mu += yl[(b*64 + t)*3 + ch];
    mu *= (1.f/30.f);
    float v = 0.f;
    for (int b=0;b<10;b++)
      for (int ch=0;ch<3;ch++){ float d = yl[(b*64+t)*3+ch] - mu; v += d*d; }
    v *= (1.f/30.f);
    float rs = rsqrtf(v + 1e-5f);
    float a = gamma[t]*rs;
    af[t] = a; bfv[t] = beta[t] - mu*a;
  }
  __syncthreads();
  if (t < 30){
    int b = t/3, ch = t - b*3;
    float mx = -1e30f, mn = 1e30f;
    for (int f=0; f<64; f++){
      float v = yl[(b*64+f)*3+ch]*af[f] + bfv[f];
      tsb[b][ch][f] = v;
      mx = fmaxf(mx, v); mn = fminf(mn, v);
    }
    rngL[b][ch] = mx - mn;
  }
  __syncthreads();
  if (t < 10){
    #pragma unroll
    for (int ch=0; ch<3; ch++){
      float rc = rngL[t][ch];
      int rank = 0;
      #pragma unroll
      for (int c2=0; c2<3; c2++){
        float r2 = rngL[t][c2];
        if (r2 < rc || (r2 == rc && c2 < ch)) rank++;   // stable argsort ascending
      }
      perm[t][rank] = ch;
    }
  }
  __syncthreads();
  for (int idx=t; idx<3072; idx+=256){
    int r = idx>>10, rem = idx & 1023, f = rem>>4, b = rem & 15;
    float v = 0.f;
    if (b < 10) v = tsb[b][perm[b][r]][f];
    seq[idx] = v;
  }
}

// ================= 3 RNNs: h' = tanh(x*wih + bih + h@Whh^T + bhh), 64 steps =================
// one block per RNN; 8 waves; Whh split-bf16 fragments resident in VGPRs; h in swizzled LDS hi/lo
__global__ __launch_bounds__(512) void k_rnn(const unsigned short* __restrict__ whh_h,
                                             const unsigned short* __restrict__ whh_l,
                                             const float* __restrict__ seq,
                                             const float* __restrict__ Wih,
                                             const float* __restrict__ bih,
                                             const float* __restrict__ bhh,
                                             float* __restrict__ lasts){
  __shared__ __align__(16) char hsm[16384];   // h hi [16][256] bf16 swizzled | lo at +8192
  int rnn = blockIdx.x;
  int t = threadIdx.x, w = t>>6, l = t&63;
  bf16x8 Bh[2][8], Bl[2][8];                  // wave w owns n-tiles 2w, 2w+1
  #pragma unroll
  for (int q=0;q<2;q++){
    int nt = 2*w + q;
    #pragma unroll
    for (int kt=0;kt<8;kt++){
      size_t fi = (((((size_t)rnn*16 + nt)*8) + kt)*64 + l)*8;
      Bh[q][kt] = *(const bf16x8*)(whh_h + fi);
      Bl[q][kt] = *(const bf16x8*)(whh_l + fi);
    }
  }
  int o0 = (2*w)*16 + (l&15), o1 = o0 + 16;
  float wih0 = Wih[rnn*256 + o0], wih1 = Wih[rnn*256 + o1];
  float bs0 = bih[rnn*256+o0] + bhh[rnn*256+o0];
  float bs1 = bih[rnn*256+o1] + bhh[rnn*256+o1];
  float4 z4 = {0.f,0.f,0.f,0.f};
  for (int i=t; i<1024; i+=512) ((float4*)hsm)[i] = z4;   // h = 0
  __syncthreads();
  int arow = l&15, colb = (l>>4)<<4, sw = (arow&7)<<4;
  int b_base = (l>>4)<<2;
  for (int step=0; step<64; step++){
    f32x4 a0 = (f32x4){0.f,0.f,0.f,0.f};
    f32x4 a1 = (f32x4){0.f,0.f,0.f,0.f};
    #pragma unroll
    for (int kt=0; kt<8; kt++){
      int off = ((arow<<9) + (kt<<6) + colb) ^ sw;
      bf16x8 ahv = *(const bf16x8*)(hsm + off);
      bf16x8 alv = *(const bf16x8*)(hsm + 8192 + off);
      a0 = MFMA16(ahv, Bh[0][kt], a0);
      a0 = MFMA16(ahv, Bl[0][kt], a0);
      a0 = MFMA16(alv, Bh[0][kt], a0);
      a1 = MFMA16(ahv, Bh[1][kt], a1);
      a1 = MFMA16(ahv, Bl[1][kt], a1);
      a1 = MFMA16(alv, Bh[1][kt], a1);
    }
    __syncthreads();   // all h reads consumed before overwrite
    #pragma unroll
    for (int reg=0; reg<4; reg++){
      int b = b_base + reg;
      float xv = seq[rnn*1024 + step*16 + b];
      float p0 = a0[reg] + xv*wih0 + bs0;
      float p1 = a1[reg] + xv*wih1 + bs1;
      float h0 = tanh_fast(p0), h1 = tanh_fast(p1);
      int wsw = (b&7)<<4;
      int off0 = ((b<<9) + (o0<<1)) ^ wsw;
      int off1 = ((b<<9) + (o1<<1)) ^ wsw;
      unsigned short hh0 = f2bf(h0); unsigned short hl0 = f2bf(h0 - bf2f(hh0));
      unsigned short hh1 = f2bf(h1); unsigned short hl1 = f2bf(h1 - bf2f(hh1));
      *(unsigned short*)(hsm + off0) = hh0;
      *(unsigned short*)(hsm + 8192 + off0) = hl0;
      *(unsigned short*)(hsm + off1) = hh1;
      *(unsigned short*)(hsm + 8192 + off1) = hl1;
      if (step == 63){
        lasts[((size_t)rnn*16 + b)*256 + o0] = h0;
        lasts[((size_t)rnn*16 + b)*256 + o1] = h1;
      }
    }
    __syncthreads();
  }
}

// ================= head: avg over 3 RNNs, @ Wl^T + bl -> out[10][5] =================
__global__ __launch_bounds__(512) void k_head(const float* __restrict__ lasts,
                                              const float* __restrict__ Wl,
                                              const float* __restrict__ bl,
                                              float* __restrict__ out){
  int t = threadIdx.x;
  if (t < 400){
    int oidx = t>>3, l8 = t&7;       // 50 outputs x 8 lanes
    int b = oidx/5, c = oidx - b*5;
    float s = 0.f;
    for (int i=0;i<32;i++){
      int o = (l8<<5) + i;
      float avg = (lasts[(size_t)(0*16+b)*256+o] + lasts[(size_t)(1*16+b)*256+o]
                 + lasts[(size_t)(2*16+b)*256+o]) * (1.f/3.f);
      s += avg * Wl[c*256 + o];
    }
    #pragma unroll
    for (int d=1; d<8; d<<=1) s += __shfl_xor(s, d);
    if (l8 == 0) out[oidx] = s + bl[c];
  }
}

extern "C" void kernel_launch(void* const* d_in, const int* in_sizes, int n_in,
                              void* d_out, int out_size, void* d_ws, size_t ws_size,
                              hipStream_t stream){
  const float* x    = (const float*)d_in[0];
  const float* W1   = (const float*)d_in[1];
  const float* b1   = (const float*)d_in[2];
  const float* W2   = (const float*)d_in[3];
  const float* b2   = (const float*)d_in[4];
  const float* gamma= (const float*)d_in[5];
  const float* beta = (const float*)d_in[6];
  const float* Wih  = (const float*)d_in[7];
  const float* Whh  = (const float*)d_in[8];
  const float* bih  = (const float*)d_in[9];
  const float* bhh  = (const float*)d_in[10];
  const float* Wl   = (const float*)d_in[11];
  const float* bl   = (const float*)d_in[12];
  char* ws = (char*)d_ws;
  unsigned short* w1h  = (unsigned short*)(ws + WS_W1H);
  unsigned short* w1l  = (unsigned short*)(ws + WS_W1L);
  unsigned short* whhh = (unsigned short*)(ws + WS_WHHH);
  unsigned short* whhl = (unsigned short*)(ws + WS_WHHL);
  float* y1   = (float*)(ws + WS_Y1);
  float* y2   = (float*)(ws + WS_Y2);
  float* seq  = (float*)(ws + WS_SEQ);
  float* last = (float*)(ws + WS_LAST);

  hipLaunchKernelGGL(k_prep,  dim3(104),  dim3(256), 0, stream, W1, Whh, w1h, w1l, whhh, whhl);
  hipLaunchKernelGGL(k_conv1, dim3(3200), dim3(256), 0, stream, x, b1, w1h, w1l, y1);
  hipLaunchKernelGGL(k_conv2, dim3(640),  dim3(256), 0, stream, y1, W2, b2, y2);
  hipLaunchKernelGGL(k_bn,    dim3(1),    dim3(256), 0, stream, y2, gamma, beta, seq);
  hipLaunchKernelGGL(k_rnn,   dim3(3),    dim3(512), 0, stream, whhh, whhl, seq, Wih, bih, bhh, last);
  hipLaunchKernelGGL(k_head,  dim3(1),    dim3(512), 0, stream, last, Wl, bl, (float*)d_out);
}

// Round 2
// 193.386 us; speedup vs baseline: 1.2941x; 1.2941x over previous
//
#include <hip/hip_runtime.h>

typedef __attribute__((ext_vector_type(8))) short bf16x8;
typedef __attribute__((ext_vector_type(4))) float f32x4;

#define MFMA16(a,b,c) __builtin_amdgcn_mfma_f32_16x16x32_bf16((a),(b),(c),0,0,0)

__device__ __forceinline__ unsigned short f2bf(float f){
  unsigned int u = __float_as_uint(f);
  unsigned int r = (u + 0x7fffu + ((u>>16)&1u)) >> 16;
  return (unsigned short)r;
}
__device__ __forceinline__ float bf2f(unsigned short h){
  return __uint_as_float(((unsigned int)h)<<16);
}
__device__ __forceinline__ float tanh_fast(float x){
  float e = __expf(2.f*x);
  return 1.f - 2.f/(e + 1.f);
}

// ---- workspace byte offsets (unchanged from passing version) ----
#define WS_W1H   0u           // [4 mt][8 kt][64 lane][8] bf16 hi  (32768 B)
#define WS_W1L   32768u
#define WS_WHHH  65536u       // [3][16 nt][8 kt][64][8] bf16 hi   (393216 B)
#define WS_WHHL  458752u
#define WS_Y1    851968u      // [640][64][10][10] f32             (16384000 B)
#define WS_Y2    17235968u    // [640][3] f32
#define WS_SEQ   17243648u    // [3][64][16] f32
#define WS_LAST  17255936u    // [3][16][256] f32

// ================= prep: split W1 / Whh into MFMA fragment layout =================
__global__ __launch_bounds__(256) void k_prep(const float* __restrict__ W1,
                                              const float* __restrict__ Whh,
                                              unsigned short* __restrict__ w1h,
                                              unsigned short* __restrict__ w1l,
                                              unsigned short* __restrict__ whh_h,
                                              unsigned short* __restrict__ whh_l){
  int t = blockIdx.x*256 + threadIdx.x;
  if (t < 2048){
    int l = t & 63, kt = (t>>6)&7, mt = t>>9;
    int co = mt*16 + (l&15);
    int k0 = kt*32 + ((l>>4)<<3);
    bf16x8 hv, lv;
    #pragma unroll
    for (int j=0;j<8;j++){
      int k = k0 + j;
      float v = (k < 243) ? W1[co*243 + k] : 0.f;
      unsigned short h = f2bf(v);
      unsigned short lo = f2bf(v - bf2f(h));
      hv[j] = (short)h; lv[j] = (short)lo;
    }
    *(bf16x8*)(w1h + (size_t)t*8) = hv;
    *(bf16x8*)(w1l + (size_t)t*8) = lv;
  } else if (t < 2048 + 24576){
    int u = t - 2048;
    int l = u & 63, kt = (u>>6)&7, nt = (u>>9)&15, rnn = u>>13;
    int o = nt*16 + (l&15);
    int k0 = kt*32 + ((l>>4)<<3);
    const float* src = Whh + ((size_t)rnn*256 + o)*256;
    bf16x8 hv, lv;
    #pragma unroll
    for (int j=0;j<8;j++){
      float v = src[k0 + j];
      unsigned short h = f2bf(v);
      unsigned short lo = f2bf(v - bf2f(h));
      hv[j] = (short)h; lv[j] = (short)lo;
    }
    *(bf16x8*)(whh_h + (size_t)u*8) = hv;
    *(bf16x8*)(whh_l + (size_t)u*8) = lv;
  }
}

// ================= conv1 (9x9 stride 9) + bias + relu + 2x2 maxpool =================
// block = (frame, oy-pair g): 40 patches (2 patch-rows), 256 thr = 4 waves = 4 co tiles
// LDS 40960 B: Bhi[40][256]bf16 @0, Blo @20480 (XOR-swizzled); pool[64][41]f32 overlaid after
__global__ __launch_bounds__(256,4) void k_conv1(const float* __restrict__ x,
                                                 const float* __restrict__ b1,
                                                 const unsigned short* __restrict__ w1h,
                                                 const unsigned short* __restrict__ w1l,
                                                 float* __restrict__ y1){
  __shared__ __align__(16) char smem[40960];
  int fr = blockIdx.x / 10, g = blockIdx.x % 10;
  int t = threadIdx.x, w = t>>6, l = t&63;

  // A = W1 fragments (split), one mt per wave
  bf16x8 ah[8], al[8];
  #pragma unroll
  for (int kt=0; kt<8; kt++){
    size_t fi = (((size_t)(w*8 + kt))*64 + l)*8;
    ah[kt] = *(const bf16x8*)(w1h + fi);
    al[kt] = *(const bf16x8*)(w1l + fi);
  }
  float bias[4];
  #pragma unroll
  for (int reg=0;reg<4;reg++) bias[reg] = b1[w*16 + ((l>>4)<<2) + reg];

  // stage 18 rows x 180 cols x 3c -> [patch][k] truncation-split bf16, swizzled
  const float4* xb4 = (const float4*)x + (size_t)fr*24300 + (size_t)g*810;
  for (int i=t; i<2430; i+=256){
    int c = i/810;
    int rem = i - c*810;
    int rl = rem/45;
    int quad = rem - rl*45;
    int oyl = (rl >= 9) ? 1 : 0;
    int ky = rl - 9*oyl;
    float4 v4 = xb4[c*8100 + rem];
    int kbase = c*81 + ky*9;
    int col0 = quad<<2;
    int ox = (col0*57)>>9;            // floor(col0/9), valid for col0<180
    int kx = col0 - 9*ox;
    int p = oyl*20 + ox;
    float vv[4] = {v4.x, v4.y, v4.z, v4.w};
    #pragma unroll
    for (int q=0;q<4;q++){
      int k = kbase + kx;
      int off = ((p<<9) + (k<<1)) ^ ((p&7)<<4);
      unsigned int u = __float_as_uint(vv[q]);
      *(unsigned short*)(smem + off) = (unsigned short)(u>>16);
      float lof = vv[q] - __uint_as_float(u & 0xffff0000u);
      *(unsigned short*)(smem + 20480 + off) = (unsigned short)(__float_as_uint(lof)>>16);
      kx++; if (kx==9){ kx=0; p++; }
    }
  }
  // zero pad k in [243,256): 40 patches x 13 k x (hi,lo)
  for (int i=t; i<520; i+=256){
    int p = i/13, k = 243 + (i - p*13);
    int off = ((p<<9) + (k<<1)) ^ ((p&7)<<4);
    *(unsigned short*)(smem + off) = 0;
    *(unsigned short*)(smem + 20480 + off) = 0;
  }
  __syncthreads();

  // MFMA: tiles cover patches {0..15, 16..31, 24..39} (tile2 overlaps tile1; dups not stored)
  const int pbase[3] = {0, 16, 24};
  int colb = (l>>4)<<4;
  f32x4 acc[3];
  #pragma unroll
  for (int nt=0;nt<3;nt++) acc[nt] = (f32x4){0.f,0.f,0.f,0.f};
  #pragma unroll
  for (int nt=0; nt<3; nt++){
    int p = pbase[nt] + (l&15);
    int sw = (p&7)<<4;
    #pragma unroll
    for (int kt=0; kt<8; kt++){
      int off = ((p<<9) + (kt<<6) + colb) ^ sw;
      bf16x8 bh  = *(const bf16x8*)(smem + off);
      bf16x8 blo = *(const bf16x8*)(smem + 20480 + off);
      acc[nt] = MFMA16(ah[kt], bh,  acc[nt]);
      acc[nt] = MFMA16(ah[kt], blo, acc[nt]);
      acc[nt] = MFMA16(al[kt], bh,  acc[nt]);
    }
  }
  __syncthreads();           // B reads done; overlay pool buffer

  float* poolb = (float*)smem;        // [64][41] f32 (padded stride kills conflicts)
  #pragma unroll
  for (int nt=0;nt<3;nt++){
    int m = l&15;
    int p = pbase[nt] + m;
    #pragma unroll
    for (int reg=0;reg<4;reg++){
      int co = w*16 + ((l>>4)<<2) + reg;   // C/D: col=lane&15 (patch), row=4*(lane>>4)+reg (co)
      float v = fmaxf(acc[nt][reg] + bias[reg], 0.f);
      if (nt != 2 || m >= 8) poolb[co*41 + p] = v;
    }
  }
  __syncthreads();
  for (int idx=t; idx<640; idx+=256){
    int co = idx/10, xp = idx - co*10;
    const float* pb = poolb + co*41;
    float m = fmaxf(fmaxf(pb[2*xp], pb[2*xp+1]), fmaxf(pb[20+2*xp], pb[21+2*xp]));
    y1[(size_t)fr*6400 + co*100 + g*10 + xp] = m;
  }
}

// ================= conv2 (5x5 stride 5) + bias + relu + 2x2 maxpool -> y[640][3] =================
__global__ __launch_bounds__(256) void k_conv2(const float* __restrict__ y1,
                                               const float* __restrict__ W2,
                                               const float* __restrict__ b2,
                                               float* __restrict__ y2){
  __shared__ float yl[6400];
  __shared__ float w2s[4800];
  int fr = blockIdx.x, t = threadIdx.x;
  const float4* src = (const float4*)(y1 + (size_t)fr*6400);
  for (int i=t;i<1600;i+=256) ((float4*)yl)[i] = src[i];
  for (int i=t;i<1200;i+=256) ((float4*)w2s)[i] = ((const float4*)W2)[i];
  __syncthreads();
  if (t < 192){
    int o = t>>4, l16 = t&15;
    int ch = o>>2, pos = o&3;
    int oy = pos>>1, ox = pos&1;
    float s = 0.f;
    for (int i=0;i<100;i++){
      int k = l16 + (i<<4);
      int ci = k/25; int r = k - ci*25; int ky = r/5, kx = r - ky*5;
      s += yl[ci*100 + (5*oy+ky)*10 + 5*ox + kx] * w2s[ch*1600 + k];
    }
    #pragma unroll
    for (int d=1; d<16; d<<=1) s += __shfl_xor(s, d);
    float v = fmaxf(s + b2[ch], 0.f);
    v = fmaxf(v, __shfl_xor(v, 16));
    v = fmaxf(v, __shfl_xor(v, 32));
    if ((t&63)==0) y2[fr*3 + (t>>6)] = v;
  }
}

// ================= BN (train) + per-sample range sort + build seqs[3][64][16] =================
__global__ __launch_bounds__(256) void k_bn(const float* __restrict__ y2,
                                            const float* __restrict__ gamma,
                                            const float* __restrict__ beta,
                                            float* __restrict__ seq){
  __shared__ float yl[1920];
  __shared__ float af[64], bfv[64];
  __shared__ float tsb[10][3][64];
  __shared__ float rngL[10][3];
  __shared__ int   perm[10][3];
  int t = threadIdx.x;
  for (int i=t;i<1920;i+=256) yl[i] = y2[i];
  __syncthreads();
  if (t < 64){
    float mu = 0.f;
    for (int b=0;b<10;b++)
      for (int ch=0;ch<3;ch++) mu += yl[(b*64 + t)*3 + ch];
    mu *= (1.f/30.f);
    float v = 0.f;
    for (int b=0;b<10;b++)
      for (int ch=0;ch<3;ch++){ float d = yl[(b*64+t)*3+ch] - mu; v += d*d; }
    v *= (1.f/30.f);
    float rs = rsqrtf(v + 1e-5f);
    float a = gamma[t]*rs;
    af[t] = a; bfv[t] = beta[t] - mu*a;
  }
  __syncthreads();
  if (t < 30){
    int b = t/3, ch = t - b*3;
    float mx = -1e30f, mn = 1e30f;
    for (int f=0; f<64; f++){
      float v = yl[(b*64+f)*3+ch]*af[f] + bfv[f];
      tsb[b][ch][f] = v;
      mx = fmaxf(mx, v); mn = fminf(mn, v);
    }
    rngL[b][ch] = mx - mn;
  }
  __syncthreads();
  if (t < 10){
    #pragma unroll
    for (int ch=0; ch<3; ch++){
      float rc = rngL[t][ch];
      int rank = 0;
      #pragma unroll
      for (int c2=0; c2<3; c2++){
        float r2 = rngL[t][c2];
        if (r2 < rc || (r2 == rc && c2 < ch)) rank++;   // stable argsort ascending
      }
      perm[t][rank] = ch;
    }
  }
  __syncthreads();
  for (int idx=t; idx<3072; idx+=256){
    int r = idx>>10, rem = idx & 1023, f = rem>>4, b = rem & 15;
    float v = 0.f;
    if (b < 10) v = tsb[b][perm[b][r]][f];
    seq[idx] = v;
  }
}

// ================= 3 RNNs: h' = tanh(x*wih + bih + h@Whh^T + bhh), 64 steps =================
// one block per RNN; 8 waves; Whh split-bf16 frags in VGPRs; h double-buffered in swizzled LDS;
// 6 independent MFMA accumulator chains; seq staged in LDS; 1 barrier/step
__global__ __launch_bounds__(512) void k_rnn(const unsigned short* __restrict__ whh_h,
                                             const unsigned short* __restrict__ whh_l,
                                             const float* __restrict__ seq,
                                             const float* __restrict__ Wih,
                                             const float* __restrict__ bih,
                                             const float* __restrict__ bhh,
                                             float* __restrict__ lasts){
  __shared__ __align__(16) char hsm[36864];  // buf0 @0 (hi|lo 8K+8K), buf1 @16384, seqL @32768 (4KB)
  float* seqL = (float*)(hsm + 32768);
  int rnn = blockIdx.x;
  int t = threadIdx.x, w = t>>6, l = t&63;
  bf16x8 Bh[2][8], Bl[2][8];                 // wave w owns n-tiles 2w, 2w+1
  #pragma unroll
  for (int q=0;q<2;q++){
    int nt = 2*w + q;
    #pragma unroll
    for (int kt=0;kt<8;kt++){
      size_t fi = (((((size_t)rnn*16 + nt)*8) + kt)*64 + l)*8;
      Bh[q][kt] = *(const bf16x8*)(whh_h + fi);
      Bl[q][kt] = *(const bf16x8*)(whh_l + fi);
    }
  }
  int o0 = (2*w)*16 + (l&15), o1 = o0 + 16;
  float wih0 = Wih[rnn*256 + o0], wih1 = Wih[rnn*256 + o1];
  float bs0 = bih[rnn*256+o0] + bhh[rnn*256+o0];
  float bs1 = bih[rnn*256+o1] + bhh[rnn*256+o1];
  for (int i=t; i<1024; i+=512) seqL[i] = seq[rnn*1024 + i];
  float4 z4 = {0.f,0.f,0.f,0.f};
  for (int i=t; i<1024; i+=512) ((float4*)hsm)[i] = z4;   // zero buf0 (h=0)
  __syncthreads();
  int arow = l&15, colb = (l>>4)<<4, sw = (arow&7)<<4;
  int b_base = (l>>4)<<2;
  for (int step=0; step<64; step++){
    char* cur = hsm + ((step&1)<<14);
    char* nxt = hsm + (((step+1)&1)<<14);
    f32x4 p0=(f32x4){0,0,0,0}, q0=p0, r0=p0, p1=p0, q1=p0, r1=p0;
    #pragma unroll
    for (int kt=0; kt<8; kt++){
      int off = ((arow<<9) + (kt<<6) + colb) ^ sw;
      bf16x8 ahv = *(const bf16x8*)(cur + off);
      bf16x8 alv = *(const bf16x8*)(cur + 8192 + off);
      p0 = MFMA16(ahv, Bh[0][kt], p0);
      q0 = MFMA16(ahv, Bl[0][kt], q0);
      r0 = MFMA16(alv, Bh[0][kt], r0);
      p1 = MFMA16(ahv, Bh[1][kt], p1);
      q1 = MFMA16(ahv, Bl[1][kt], q1);
      r1 = MFMA16(alv, Bh[1][kt], r1);
    }
    float4 sx = *(const float4*)(seqL + (step<<4) + b_base);
    float sxa[4] = {sx.x, sx.y, sx.z, sx.w};
    #pragma unroll
    for (int reg=0; reg<4; reg++){
      int b = b_base + reg;
      float a0 = (p0[reg] + q0[reg]) + r0[reg];
      float a1 = (p1[reg] + q1[reg]) + r1[reg];
      float h0 = tanh_fast(a0 + sxa[reg]*wih0 + bs0);
      float h1 = tanh_fast(a1 + sxa[reg]*wih1 + bs1);
      int wsw = (b&7)<<4;
      int off0 = ((b<<9) + (o0<<1)) ^ wsw;
      int off1 = ((b<<9) + (o1<<1)) ^ wsw;
      unsigned int u0 = __float_as_uint(h0);
      unsigned int u1 = __float_as_uint(h1);
      *(unsigned short*)(nxt + off0) = (unsigned short)(u0>>16);
      float l0 = h0 - __uint_as_float(u0 & 0xffff0000u);
      *(unsigned short*)(nxt + 8192 + off0) = (unsigned short)(__float_as_uint(l0)>>16);
      *(unsigned short*)(nxt + off1) = (unsigned short)(u1>>16);
      float l1 = h1 - __uint_as_float(u1 & 0xffff0000u);
      *(unsigned short*)(nxt + 8192 + off1) = (unsigned short)(__float_as_uint(l1)>>16);
      if (step == 63){
        lasts[((size_t)rnn*16 + b)*256 + o0] = h0;
        lasts[((size_t)rnn*16 + b)*256 + o1] = h1;
      }
    }
    __syncthreads();
  }
}

// ================= head: avg over 3 RNNs, @ Wl^T + bl -> out[10][5] =================
__global__ __launch_bounds__(512) void k_head(const float* __restrict__ lasts,
                                              const float* __restrict__ Wl,
                                              const float* __restrict__ bl,
                                              float* __restrict__ out){
  int t = threadIdx.x;
  if (t < 400){
    int oidx = t>>3, l8 = t&7;       // 50 outputs x 8 lanes
    int b = oidx/5, c = oidx - b*5;
    float s = 0.f;
    for (int i=0;i<32;i++){
      int o = (l8<<5) + i;
      float avg = (lasts[(size_t)(0*16+b)*256+o] + lasts[(size_t)(1*16+b)*256+o]
                 + lasts[(size_t)(2*16+b)*256+o]) * (1.f/3.f);
      s += avg * Wl[c*256 + o];
    }
    #pragma unroll
    for (int d=1; d<8; d<<=1) s += __shfl_xor(s, d);
    if (l8 == 0) out[oidx] = s + bl[c];
  }
}

extern "C" void kernel_launch(void* const* d_in, const int* in_sizes, int n_in,
                              void* d_out, int out_size, void* d_ws, size_t ws_size,
                              hipStream_t stream){
  const float* x    = (const float*)d_in[0];
  const float* W1   = (const float*)d_in[1];
  const float* b1   = (const float*)d_in[2];
  const float* W2   = (const float*)d_in[3];
  const float* b2   = (const float*)d_in[4];
  const float* gamma= (const float*)d_in[5];
  const float* beta = (const float*)d_in[6];
  const float* Wih  = (const float*)d_in[7];
  const float* Whh  = (const float*)d_in[8];
  const float* bih  = (const float*)d_in[9];
  const float* bhh  = (const float*)d_in[10];
  const float* Wl   = (const float*)d_in[11];
  const float* bl   = (const float*)d_in[12];
  char* ws = (char*)d_ws;
  unsigned short* w1h  = (unsigned short*)(ws + WS_W1H);
  unsigned short* w1l  = (unsigned short*)(ws + WS_W1L);
  unsigned short* whhh = (unsigned short*)(ws + WS_WHHH);
  unsigned short* whhl = (unsigned short*)(ws + WS_WHHL);
  float* y1   = (float*)(ws + WS_Y1);
  float* y2   = (float*)(ws + WS_Y2);
  float* seq  = (float*)(ws + WS_SEQ);
  float* last = (float*)(ws + WS_LAST);

  hipLaunchKernelGGL(k_prep,  dim3(104),  dim3(256), 0, stream, W1, Whh, w1h, w1l, whhh, whhl);
  hipLaunchKernelGGL(k_conv1, dim3(6400), dim3(256), 0, stream, x, b1, w1h, w1l, y1);
  hipLaunchKernelGGL(k_conv2, dim3(640),  dim3(256), 0, stream, y1, W2, b2, y2);
  hipLaunchKernelGGL(k_bn,    dim3(1),    dim3(256), 0, stream, y2, gamma, beta, seq);
  hipLaunchKernelGGL(k_rnn,   dim3(3),    dim3(512), 0, stream, whhh, whhl, seq, Wih, bih, bhh, last);
  hipLaunchKernelGGL(k_head,  dim3(1),    dim3(512), 0, stream, last, Wl, bl, (float*)d_out);
}